// Round 5
// baseline (1167.591 us; speedup 1.0000x reference)
//
#include <hip/hip_runtime.h>
#include <math.h>

#define TT   512
#define BB   512
#define DIN  64
#define DLAT 128
#define KKK  192                 // DLAT + DIN

typedef _Float16 half8 __attribute__((ext_vector_type(8)));
typedef float    f32x4 __attribute__((ext_vector_type(4)));

#define MFMA16(A, B, C) __builtin_amdgcn_mfma_f32_16x16x32_f16((A), (B), (C), 0, 0, 0)

// LDS-only barrier: no vmcnt(0) drain (out-stores / x-loads stay in flight).
#define BAR() asm volatile("s_waitcnt lgkmcnt(0)\n\ts_barrier" ::: "memory")

__device__ __forceinline__ float fsigmoid(float x) {
    float e = __builtin_amdgcn_exp2f(-1.44269504f * x);
    return __builtin_amdgcn_rcpf(1.f + e);
}
__device__ __forceinline__ float ftanh(float x) {
    float e = __builtin_amdgcn_exp2f(2.88539008f * x);
    return 1.f - 2.f * __builtin_amdgcn_rcpf(1.f + e);
}
__device__ __forceinline__ half8 cvt8(float4 a, float4 b) {
    return (half8){(_Float16)a.x, (_Float16)a.y, (_Float16)a.z, (_Float16)a.w,
                   (_Float16)b.x, (_Float16)b.y, (_Float16)b.z, (_Float16)b.w};
}

// Persistent GRU: 32 blocks x 512 threads (8 waves = 2/SIMD). Block owns 16
// batch rows. Wave w owns gate cols [16w,16w+16) for z, r AND cand, so h,
// zz, cand live in the same C-layout lane slots across phases. Weights are
// register-resident B-frags (f16, 18 half8/wave). LDS: h and h*r f16
// A-operand tiles (row-padded [16][136]); x A-frags load straight to regs.
__global__ __launch_bounds__(512, 2) void gru_mfma(
    const float* __restrict__ seqs, const float* __restrict__ h0,
    const float* __restrict__ bz, const float* __restrict__ br,
    const float* __restrict__ bi,
    const float* __restrict__ Wz, const float* __restrict__ Wr,
    const float* __restrict__ Wi, float* __restrict__ out)
{
    __shared__ __align__(16) _Float16 hA [16][136];
    __shared__ __align__(16) _Float16 hrA[16][136];

    const int tid = threadIdx.x;
    const int w   = tid >> 6;          // wave 0..7
    const int l   = tid & 63;
    const int q   = l >> 4;            // frag k-group
    const int ln  = l & 15;            // frag row/col index
    const int b0  = (int)blockIdx.x * 16;
    const int nc  = 16 * w + ln;       // this thread's gate column

    // ---- weight fragments -> registers (one-time) ----
    half8 wz[6], wr[6], wi[6];
    #pragma unroll
    for (int kt = 0; kt < 6; ++kt) {
        const int k0 = kt * 32 + q * 8;
        wz[kt] = cvt8(*(const float4*)&Wz[nc * KKK + k0],
                      *(const float4*)&Wz[nc * KKK + k0 + 4]);
        wr[kt] = cvt8(*(const float4*)&Wr[nc * KKK + k0],
                      *(const float4*)&Wr[nc * KKK + k0 + 4]);
        wi[kt] = cvt8(*(const float4*)&Wi[nc * KKK + k0],
                      *(const float4*)&Wi[nc * KKK + k0 + 4]);
    }
    const float bzv = bz[nc], brv = br[nc], biv = bi[nc];

    // ---- h state in registers (C-layout slots) + hA + out[0] ----
    float h[4];
    #pragma unroll
    for (int i = 0; i < 4; ++i)
        h[i] = h0[(size_t)(b0 + 4 * q + i) * DLAT + nc];

    for (int idx = tid; idx < 16 * DLAT; idx += 512) {
        const int m = idx >> 7, c = idx & 127;
        const float v = h0[(size_t)(b0 + m) * DLAT + c];
        out[(size_t)(b0 + m) * DLAT + c] = v;
        hA[m][c] = (_Float16)v;
    }

    // ---- x[0] A-frags direct to registers ----
    const float* xb0 = seqs + ((size_t)0 * BB + b0 + ln) * DIN + q * 8;
    half8 xf0 = cvt8(*(const float4*)xb0,        *(const float4*)(xb0 + 4));
    half8 xf1 = cvt8(*(const float4*)(xb0 + 32), *(const float4*)(xb0 + 36));

    __syncthreads();

    // per-thread out pointer: first store goes to out[t=1]
    float* optr = out + (size_t)BB * DLAT + (size_t)(b0 + 4 * q) * DLAT + nc;

    for (int t = 0; t < TT; ++t) {
        // prefetch x[t+1] A-frags (consumed next step)
        float4 nx0, nx1, nx2, nx3;
        const bool havext = (t + 1 < TT);
        if (havext) {
            const float* nb = seqs + ((size_t)(t + 1) * BB + b0 + ln) * DIN + q * 8;
            nx0 = *(const float4*)nb;        nx1 = *(const float4*)(nb + 4);
            nx2 = *(const float4*)(nb + 32); nx3 = *(const float4*)(nb + 36);
        }

        // ---- phase 1: z, r fully; cand's x-part (r-independent) ----
        half8 a0 = *(const half8*)&hA[ln][ 0 + q * 8];
        half8 a1 = *(const half8*)&hA[ln][32 + q * 8];
        half8 a2 = *(const half8*)&hA[ln][64 + q * 8];
        half8 a3 = *(const half8*)&hA[ln][96 + q * 8];

        f32x4 az = (f32x4){bzv, bzv, bzv, bzv};
        f32x4 ar = (f32x4){brv, brv, brv, brv};
        f32x4 ai = (f32x4){biv, biv, biv, biv};

        az = MFMA16(a0, wz[0], az);
        az = MFMA16(a1, wz[1], az);
        az = MFMA16(a2, wz[2], az);
        az = MFMA16(a3, wz[3], az);
        az = MFMA16(xf0, wz[4], az);
        az = MFMA16(xf1, wz[5], az);
        ar = MFMA16(a0, wr[0], ar);
        ar = MFMA16(a1, wr[1], ar);
        ar = MFMA16(a2, wr[2], ar);
        ar = MFMA16(a3, wr[3], ar);
        ar = MFMA16(xf0, wr[4], ar);
        ar = MFMA16(xf1, wr[5], ar);
        ai = MFMA16(xf0, wi[4], ai);
        ai = MFMA16(xf1, wi[5], ai);

        float zz[4];
        #pragma unroll
        for (int i = 0; i < 4; ++i) {
            zz[i]         = fsigmoid(az[i]);
            const float r = fsigmoid(ar[i]);
            hrA[4 * q + i][nc] = (_Float16)(h[i] * r);
        }

        BAR();   // hr visible (LDS only; out-stores/x-loads stay in flight)

        // ---- phase 2: cand h*r part ----
        half8 c0 = *(const half8*)&hrA[ln][ 0 + q * 8];
        half8 c1 = *(const half8*)&hrA[ln][32 + q * 8];
        half8 c2 = *(const half8*)&hrA[ln][64 + q * 8];
        half8 c3 = *(const half8*)&hrA[ln][96 + q * 8];
        ai = MFMA16(c0, wi[0], ai);
        ai = MFMA16(c1, wi[1], ai);
        ai = MFMA16(c2, wi[2], ai);
        ai = MFMA16(c3, wi[3], ai);

        #pragma unroll
        for (int i = 0; i < 4; ++i) {
            const float cand = ftanh(ai[i]);
            const float hn   = h[i] + zz[i] * (cand - h[i]);
            h[i] = hn;
            hA[4 * q + i][nc] = (_Float16)hn;
            optr[i * DLAT] = hn;
        }
        optr += (size_t)BB * DLAT;

        if (havext) { xf0 = cvt8(nx0, nx1); xf1 = cvt8(nx2, nx3); }

        BAR();   // new h visible for next step's fragments
    }
}

extern "C" void kernel_launch(void* const* d_in, const int* in_sizes, int n_in,
                              void* d_out, int out_size, void* d_ws, size_t ws_size,
                              hipStream_t stream) {
    const float* seqs = (const float*)d_in[0];
    const float* h0   = (const float*)d_in[1];
    const float* Wz   = (const float*)d_in[2];
    const float* bz   = (const float*)d_in[3];
    const float* Wr   = (const float*)d_in[4];
    const float* br   = (const float*)d_in[5];
    const float* Wi   = (const float*)d_in[6];
    const float* bi   = (const float*)d_in[7];
    float* out = (float*)d_out;

    gru_mfma<<<BB / 16, 512, 0, stream>>>(seqs, h0, bz, br, bi, Wz, Wr, Wi, out);
}

// Round 6
// 658.200 us; speedup vs baseline: 1.7739x; 1.7739x over previous
//
#include <hip/hip_runtime.h>
#include <math.h>

#define TT   512
#define BB   512
#define DIN  64
#define DLAT 128
#define KKK  192                 // DLAT + DIN

typedef _Float16 half8 __attribute__((ext_vector_type(8)));
typedef _Float16 half4 __attribute__((ext_vector_type(4)));
typedef float    f32x4 __attribute__((ext_vector_type(4)));

#define MFMA16(A, B, C) __builtin_amdgcn_mfma_f32_16x16x32_f16((A), (B), (C), 0, 0, 0)

__device__ __forceinline__ float fsigmoid(float x) {
    float e = __builtin_amdgcn_exp2f(-1.44269504f * x);
    return __builtin_amdgcn_rcpf(1.f + e);
}
__device__ __forceinline__ float ftanh(float x) {
    float e = __builtin_amdgcn_exp2f(2.88539008f * x);
    return 1.f - 2.f * __builtin_amdgcn_rcpf(1.f + e);
}
__device__ __forceinline__ half8 cvt8(float4 a, float4 b) {
    return (half8){(_Float16)a.x, (_Float16)a.y, (_Float16)a.z, (_Float16)a.w,
                   (_Float16)b.x, (_Float16)b.y, (_Float16)b.z, (_Float16)b.w};
}

// Persistent GRU: 32 blocks x 256 threads (4 waves) — the R3 measured-best
// structure. Block owns 16 batch rows. Wave w owns output cols [32w,32w+32).
// Weights register-resident as MFMA B-frags (f16). h register-resident
// (C-layout slots reused across steps). LDS: h (16x128) and h*r (16x128) f16
// A-tiles (row-padded [16][136]) + x double-buffered [2][16][72], staged with
// fully-coalesced float4 loads. __syncthreads() barriers (measured faster
// than the asm LDS-only barrier in R4).
__global__ __launch_bounds__(256, 1) void gru_mfma(
    const float* __restrict__ seqs, const float* __restrict__ h0,
    const float* __restrict__ bz, const float* __restrict__ br,
    const float* __restrict__ bi,
    const float* __restrict__ Wz, const float* __restrict__ Wr,
    const float* __restrict__ Wi, float* __restrict__ out)
{
    __shared__ __align__(16) _Float16 hA [16][136];
    __shared__ __align__(16) _Float16 hrA[16][136];
    __shared__ __align__(16) _Float16 xb [2][16][72];

    const int tid = threadIdx.x;
    const int w   = tid >> 6;          // wave 0..3
    const int l   = tid & 63;
    const int q   = l >> 4;            // frag k-group
    const int ln  = l & 15;            // frag row/col index
    const int b0  = (int)blockIdx.x * 16;

    // ---- weight fragments -> registers (one-time) ----
    half8 wz[2][6], wr[2][6], wi[2][6];
    #pragma unroll
    for (int s = 0; s < 2; ++s) {
        const int n = 32 * w + 16 * s + ln;
        #pragma unroll
        for (int kt = 0; kt < 6; ++kt) {
            const int k0 = kt * 32 + q * 8;
            wz[s][kt] = cvt8(*(const float4*)&Wz[n * KKK + k0],
                             *(const float4*)&Wz[n * KKK + k0 + 4]);
            wr[s][kt] = cvt8(*(const float4*)&Wr[n * KKK + k0],
                             *(const float4*)&Wr[n * KKK + k0 + 4]);
            wi[s][kt] = cvt8(*(const float4*)&Wi[n * KKK + k0],
                             *(const float4*)&Wi[n * KKK + k0 + 4]);
        }
    }
    float bzv[2], brv[2], biv[2];
    #pragma unroll
    for (int s = 0; s < 2; ++s) {
        const int n = 32 * w + 16 * s + ln;
        bzv[s] = bz[n]; brv[s] = br[n]; biv[s] = bi[n];
    }

    // ---- h state in registers (C-layout slots) + hA + out[0] ----
    float h[2][4];
    #pragma unroll
    for (int s = 0; s < 2; ++s)
        #pragma unroll
        for (int i = 0; i < 4; ++i)
            h[s][i] = h0[(size_t)(b0 + 4 * q + i) * DLAT + 32 * w + 16 * s + ln];

    for (int idx = tid; idx < 16 * DLAT; idx += 256) {
        const int m = idx >> 7, c = idx & 127;
        const float v = h0[(size_t)(b0 + m) * DLAT + c];
        out[(size_t)(b0 + m) * DLAT + c] = v;
        hA[m][c] = (_Float16)v;
    }
    // x[0] staged coalesced (256 threads = 16 rows x 16 float4)
    {
        const int m = tid >> 4, k4 = tid & 15;
        const float4 xv = *(const float4*)&seqs[((size_t)0 * BB + b0 + m) * DIN + k4 * 4];
        *(half4*)&xb[0][m][k4 * 4] =
            (half4){(_Float16)xv.x, (_Float16)xv.y, (_Float16)xv.z, (_Float16)xv.w};
    }
    __syncthreads();

    for (int t = 0; t < TT; ++t) {
        const int p = t & 1;

        // prefetch x[t+1] (coalesced float4; latency hidden under phase 1)
        float4 xv;
        const int xm = tid >> 4, xk = tid & 15;
        if (t + 1 < TT)
            xv = *(const float4*)&seqs[((size_t)(t + 1) * BB + b0 + xm) * DIN + xk * 4];

        // A fragments: kt 0..3 from h, kt 4..5 from x (x reused in phase 2)
        half8 a0 = *(const half8*)&hA[ln][ 0 + q * 8];
        half8 a1 = *(const half8*)&hA[ln][32 + q * 8];
        half8 a2 = *(const half8*)&hA[ln][64 + q * 8];
        half8 a3 = *(const half8*)&hA[ln][96 + q * 8];
        half8 x0 = *(const half8*)&xb[p][ln][ 0 + q * 8];
        half8 x1 = *(const half8*)&xb[p][ln][32 + q * 8];

        // ---- phase 1: z, r fully; cand's x-part (r-independent) ----
        f32x4 az[2], ar[2], ai[2];
        #pragma unroll
        for (int s = 0; s < 2; ++s) {
            az[s] = (f32x4){bzv[s], bzv[s], bzv[s], bzv[s]};
            ar[s] = (f32x4){brv[s], brv[s], brv[s], brv[s]};
            ai[s] = (f32x4){biv[s], biv[s], biv[s], biv[s]};
        }
        #pragma unroll
        for (int s = 0; s < 2; ++s) {
            az[s] = MFMA16(x0, wz[s][4], az[s]);
            az[s] = MFMA16(x1, wz[s][5], az[s]);
            ar[s] = MFMA16(x0, wr[s][4], ar[s]);
            ar[s] = MFMA16(x1, wr[s][5], ar[s]);
            ai[s] = MFMA16(x0, wi[s][4], ai[s]);
            ai[s] = MFMA16(x1, wi[s][5], ai[s]);
            az[s] = MFMA16(a0, wz[s][0], az[s]);
            az[s] = MFMA16(a1, wz[s][1], az[s]);
            az[s] = MFMA16(a2, wz[s][2], az[s]);
            az[s] = MFMA16(a3, wz[s][3], az[s]);
            ar[s] = MFMA16(a0, wr[s][0], ar[s]);
            ar[s] = MFMA16(a1, wr[s][1], ar[s]);
            ar[s] = MFMA16(a2, wr[s][2], ar[s]);
            ar[s] = MFMA16(a3, wr[s][3], ar[s]);
        }

        float zz[2][4];
        #pragma unroll
        for (int s = 0; s < 2; ++s)
            #pragma unroll
            for (int i = 0; i < 4; ++i) {
                zz[s][i]      = fsigmoid(az[s][i]);
                const float r = fsigmoid(ar[s][i]);
                hrA[4 * q + i][32 * w + 16 * s + ln] = (_Float16)(h[s][i] * r);
            }

        // stage x[t+1] into the idle buffer (its last reader was step t-1)
        if (t + 1 < TT)
            *(half4*)&xb[p ^ 1][xm][xk * 4] =
                (half4){(_Float16)xv.x, (_Float16)xv.y, (_Float16)xv.z, (_Float16)xv.w};

        __syncthreads();   // hr visible; x staged

        // ---- phase 2: cand h*r part only (4-deep) ----
        half8 c0 = *(const half8*)&hrA[ln][ 0 + q * 8];
        half8 c1 = *(const half8*)&hrA[ln][32 + q * 8];
        half8 c2 = *(const half8*)&hrA[ln][64 + q * 8];
        half8 c3 = *(const half8*)&hrA[ln][96 + q * 8];
        #pragma unroll
        for (int s = 0; s < 2; ++s) {
            ai[s] = MFMA16(c0, wi[s][0], ai[s]);
            ai[s] = MFMA16(c1, wi[s][1], ai[s]);
            ai[s] = MFMA16(c2, wi[s][2], ai[s]);
            ai[s] = MFMA16(c3, wi[s][3], ai[s]);
        }

        #pragma unroll
        for (int s = 0; s < 2; ++s)
            #pragma unroll
            for (int i = 0; i < 4; ++i) {
                const float cand = ftanh(ai[s][i]);
                const float hn   = h[s][i] + zz[s][i] * (cand - h[s][i]);
                h[s][i] = hn;
                const int m = 4 * q + i, c = 32 * w + 16 * s + ln;
                hA[m][c] = (_Float16)hn;
                out[((size_t)(t + 1) * BB + b0 + m) * DLAT + c] = hn;
            }

        __syncthreads();   // new h visible for next step's fragments
    }
}

extern "C" void kernel_launch(void* const* d_in, const int* in_sizes, int n_in,
                              void* d_out, int out_size, void* d_ws, size_t ws_size,
                              hipStream_t stream) {
    const float* seqs = (const float*)d_in[0];
    const float* h0   = (const float*)d_in[1];
    const float* Wz   = (const float*)d_in[2];
    const float* bz   = (const float*)d_in[3];
    const float* Wr   = (const float*)d_in[4];
    const float* br   = (const float*)d_in[5];
    const float* Wi   = (const float*)d_in[6];
    const float* bi   = (const float*)d_in[7];
    float* out = (float*)d_out;

    gru_mfma<<<BB / 16, 256, 0, stream>>>(seqs, h0, bz, br, bi, Wz, Wr, Wi, out);
}